// Round 2
// baseline (146.390 us; speedup 1.0000x reference)
//
#include <hip/hip_runtime.h>
#include <hip/hip_bf16.h>
#include <math.h>

// Problem constants (fixed by setup_inputs)
#define NB      2      // batch
#define T_IN    12
#define T_OUT_  24
#define O_OUT   12     // T_OUT - T_IN
#define NN      10000  // nodes
#define CC      16     // channels
#define KK      17     // neighbors
#define HH      4      // heads
#define JJ      48     // T_IN * HH
#define NPC     157    // nodes per chunk (64 chunks cover 10000)
#define NCHUNK  64

// ---- bf16 helpers (RNE pack, shift unpack) ----
__device__ __forceinline__ unsigned short f2bf(float f) {
    union { float f; unsigned int u; } v; v.f = f;
    unsigned int r = v.u + 0x7FFFu + ((v.u >> 16) & 1u);
    return (unsigned short)(r >> 16);
}
__device__ __forceinline__ float bf2f(unsigned int lo16) {
    union { unsigned int u; float f; } v; v.u = lo16 << 16;
    return v.f;
}

// ---------------- sigma = max(nearest_dists) ----------------
__global__ void sigma_reduce_kernel(const float* __restrict__ d, int n,
                                    unsigned int* __restrict__ out) {
    float m = 0.0f;  // dists are uniform [0,1): non-negative
    for (int i = blockIdx.x * blockDim.x + threadIdx.x; i < n;
         i += gridDim.x * blockDim.x)
        m = fmaxf(m, d[i]);
    #pragma unroll
    for (int off = 32; off > 0; off >>= 1)
        m = fmaxf(m, __shfl_down(m, off, 64));
    __shared__ float sm[8];
    int lane = threadIdx.x & 63, wid = threadIdx.x >> 6;
    if (lane == 0) sm[wid] = m;
    __syncthreads();
    if (threadIdx.x == 0) {
        float mm = sm[0];
        int nw = (blockDim.x + 63) >> 6;
        for (int w = 1; w < nw; ++w) mm = fmaxf(mm, sm[w]);
        atomicMax(out, __float_as_uint(mm));  // non-neg: bit order == float order
    }
}

// ---------------- precompute packed (idx, w[4] bf16) records ----------------
__global__ __launch_bounds__(256) void weights_kernel(
    const int* __restrict__ nodes, const float* __restrict__ dists,
    const unsigned int* __restrict__ sigma_bits,
    int* __restrict__ idxf, uint2* __restrict__ wpk)
{
    int i = blockIdx.x * 256 + threadIdx.x;
    if (i >= NN * KK) return;
    const float sigma  = __uint_as_float(*sigma_bits);
    const float inv_s2 = 1.0f / (sigma * sigma);
    const int   nd = nodes[i];
    const float d  = dists[i];
    const float q  = d * d * inv_s2;
    float w[HH];
    #pragma unroll
    for (int h = 0; h < HH; ++h) {
        float ww = expf(-q * (float)(h + 1) * 0.25f);
        if (nd == -1 || ww < 1e-8f) ww = 0.0f;
        w[h] = ww;
    }
    idxf[i] = (nd < 0) ? 0 : nd;
    uint2 p;
    p.x = (unsigned)f2bf(w[0]) | ((unsigned)f2bf(w[1]) << 16);
    p.y = (unsigned)f2bf(w[2]) | ((unsigned)f2bf(w[3]) << 16);
    wpk[i] = p;
}

// ---------------- phase 1: per-plane gather+aggregate (L2-resident plane) ----
// grid = 1536 blocks: XCD-swizzled so plane p lands on XCD p%8
// agg layout: (N, B, T, H, C) bf16  -> node-major for phase-2 coalescing
__global__ __launch_bounds__(256) void aggregate_kernel(
    const float* __restrict__ x,
    const int*   __restrict__ idxf,
    const uint2* __restrict__ wpk,
    float* __restrict__ out,
    unsigned short* __restrict__ agg)
{
    const int g     = blockIdx.x & 7;        // assumed XCD = blockIdx % 8
    const int sub   = blockIdx.x >> 3;       // 0..191
    const int plane = g + 8 * (sub % 3);     // 0..23, plane%8 == g
    const int chunk = sub / 3;               // 0..63
    const int t = plane % T_IN, b = plane / T_IN;
    const int n0 = chunk * NPC;
    const int n1 = (n0 + NPC < NN) ? n0 + NPC : NN;

    const float* xp = x + (b * T_IN + t) * (NN * CC);

    const int c  = threadIdx.x & 15;
    const int nl = threadIdx.x >> 4;   // 0..15

    for (int n = n0 + nl; n < n1; n += 16) {
        float a0 = 0.f, a1 = 0.f, a2 = 0.f, a3 = 0.f;
        const int rb = n * KK;
        #pragma unroll
        for (int k = 0; k < KK; ++k) {
            const int   id = idxf[rb + k];
            const uint2 wp = wpk[rb + k];
            const float gv = xp[id * CC + c];
            a0 += gv * bf2f(wp.x & 0xffffu);
            a1 += gv * bf2f(wp.x >> 16);
            a2 += gv * bf2f(wp.y & 0xffffu);
            a3 += gv * bf2f(wp.y >> 16);
        }
        unsigned short* ap = agg + (((n * NB + b) * T_IN + t) * HH * CC);
        ap[0 * CC + c] = f2bf(a0);
        ap[1 * CC + c] = f2bf(a1);
        ap[2 * CC + c] = f2bf(a2);
        ap[3 * CC + c] = f2bf(a3);
    }

    // passthrough: out[b, t, n, c] = x[b, t, n, c] (plane is L2-resident)
    const int cnt = (n1 - n0) * CC;
    float* op = out + (b * T_OUT_ + t) * (NN * CC);
    for (int i = threadIdx.x; i < cnt; i += 256) {
        const int n = n0 + (i >> 4), cc = i & 15;
        op[n * CC + cc] = xp[n * CC + cc];
    }
}

// ---------------- phase 2: 48-term shrink matmul + SELU ----------------
__global__ __launch_bounds__(384) void shrink_kernel(
    const unsigned short* __restrict__ agg,
    const float* __restrict__ Wm, const float* __restrict__ bias,
    float* __restrict__ out)
{
    const int n   = blockIdx.x;
    const int tid = threadIdx.x;

    __shared__ float a_s[NB * T_IN * HH * CC];  // 1536 floats, [b][t][h][c]
    __shared__ float W_s[O_OUT * JJ];
    __shared__ float b_s[O_OUT];

    // load this node's agg: 1536 bf16 = 3072 B contiguous, 384 x uint2
    const uint2 v = ((const uint2*)(agg + n * (NB * T_IN * HH * CC)))[tid];
    a_s[4 * tid + 0] = bf2f(v.x & 0xffffu);
    a_s[4 * tid + 1] = bf2f(v.x >> 16);
    a_s[4 * tid + 2] = bf2f(v.y & 0xffffu);
    a_s[4 * tid + 3] = bf2f(v.y >> 16);
    for (int i = tid; i < O_OUT * JJ; i += 384) W_s[i] = Wm[i];
    if (tid < O_OUT) b_s[tid] = bias[tid];
    __syncthreads();

    const int c = tid & 15;
    const int rest = tid >> 4;      // 0..23
    const int o  = rest % O_OUT;
    const int b2 = rest / O_OUT;

    float y = b_s[o];
    #pragma unroll
    for (int t = 0; t < T_IN; ++t)
        #pragma unroll
        for (int h = 0; h < HH; ++h)
            y += a_s[((b2 * T_IN + t) * HH + h) * CC + c] * W_s[o * JJ + t * HH + h];

    const float kScale = 1.0507009873554805f;
    const float kAlpha = 1.6732632423543772f;
    y = (y > 0.0f) ? kScale * y : kScale * kAlpha * expm1f(y);

    out[((b2 * T_OUT_ + T_IN + o) * NN + n) * CC + c] = y;
}

extern "C" void kernel_launch(void* const* d_in, const int* in_sizes, int n_in,
                              void* d_out, int out_size, void* d_ws, size_t ws_size,
                              hipStream_t stream) {
    const float* x     = (const float*)d_in[0];
    const int*   nodes = (const int*)  d_in[1];
    const float* dists = (const float*)d_in[2];
    const float* Wm    = (const float*)d_in[3];
    const float* bias  = (const float*)d_in[4];
    float* out = (float*)d_out;

    // ws layout: [0,4)=sigma | 256: idxf (N*K int, 680000 B) | wpk (N*K uint2,
    // 1360000 B) | agg (N*B*T*H*C bf16, 30720000 B)  => total ~32.8 MB
    char* ws = (char*)d_ws;
    unsigned int*   sigma_bits = (unsigned int*)ws;
    int*            idxf = (int*)(ws + 256);
    uint2*          wpk  = (uint2*)(ws + 256 + 680000);
    unsigned short* agg  = (unsigned short*)(ws + 256 + 680000 + 1360000);

    hipMemsetAsync(d_ws, 0, 4, stream);  // sigma slot (ws is poisoned 0xAA)

    const int nd = in_sizes[2];  // N*K
    sigma_reduce_kernel<<<256, 256, 0, stream>>>(dists, nd, sigma_bits);
    weights_kernel<<<(NN * KK + 255) / 256, 256, 0, stream>>>(
        nodes, dists, sigma_bits, idxf, wpk);
    aggregate_kernel<<<8 * 24 * 8, 256, 0, stream>>>(x, idxf, wpk, out, agg);
    shrink_kernel<<<NN, 384, 0, stream>>>(agg, Wm, bias, out);
}

// Round 3
// 126.726 us; speedup vs baseline: 1.1552x; 1.1552x over previous
//
#include <hip/hip_runtime.h>
#include <hip/hip_bf16.h>
#include <math.h>

// Problem constants (fixed by setup_inputs)
#define NB      2      // batch
#define T_IN    12
#define T_OUT_  24
#define O_OUT   12     // T_OUT - T_IN
#define NN      10000  // nodes
#define CC      16     // channels
#define KK      17     // neighbors
#define HH      4      // heads
#define JJ      48     // T_IN * HH
#define NPC     80     // nodes per chunk
#define NCHUNK  125    // 125 * 80 = 10000
#define PPG     3      // planes per group (24 planes / 8 XCD groups)

// ---- bf16 helpers (RNE pack, shift unpack) ----
__device__ __forceinline__ unsigned short f2bf(float f) {
    union { float f; unsigned int u; } v; v.f = f;
    unsigned int r = v.u + 0x7FFFu + ((v.u >> 16) & 1u);
    return (unsigned short)(r >> 16);
}
__device__ __forceinline__ float bf2f(unsigned int lo16) {
    union { unsigned int u; float f; } v; v.u = lo16 << 16;
    return v.f;
}

// ---------------- sigma = max(nearest_dists) ----------------
__global__ void sigma_reduce_kernel(const float* __restrict__ d, int n,
                                    unsigned int* __restrict__ out) {
    float m = 0.0f;  // dists are uniform [0,1): non-negative
    for (int i = blockIdx.x * blockDim.x + threadIdx.x; i < n;
         i += gridDim.x * blockDim.x)
        m = fmaxf(m, d[i]);
    #pragma unroll
    for (int off = 32; off > 0; off >>= 1)
        m = fmaxf(m, __shfl_down(m, off, 64));
    __shared__ float sm[8];
    int lane = threadIdx.x & 63, wid = threadIdx.x >> 6;
    if (lane == 0) sm[wid] = m;
    __syncthreads();
    if (threadIdx.x == 0) {
        float mm = sm[0];
        int nw = (blockDim.x + 63) >> 6;
        for (int w = 1; w < nw; ++w) mm = fmaxf(mm, sm[w]);
        atomicMax(out, __float_as_uint(mm));  // non-neg: bit order == float order
    }
}

// ---------------- precompute packed (byte-offset idx, w[4] bf16) ------------
__global__ __launch_bounds__(256) void weights_kernel(
    const int* __restrict__ nodes, const float* __restrict__ dists,
    const unsigned int* __restrict__ sigma_bits,
    int* __restrict__ idxf, uint2* __restrict__ wpk)
{
    int i = blockIdx.x * 256 + threadIdx.x;
    if (i >= NN * KK) return;
    const float sigma  = __uint_as_float(*sigma_bits);
    const float inv_s2 = 1.0f / (sigma * sigma);
    const int   nd = nodes[i];
    const float d  = dists[i];
    const float q  = d * d * inv_s2;
    float w[HH];
    #pragma unroll
    for (int h = 0; h < HH; ++h) {
        float ww = expf(-q * (float)(h + 1) * 0.25f);
        if (nd == -1 || ww < 1e-8f) ww = 0.0f;
        w[h] = ww;
    }
    idxf[i] = ((nd < 0) ? 0 : nd) * (CC * 4);  // byte offset into a plane
    uint2 p;
    p.x = (unsigned)f2bf(w[0]) | ((unsigned)f2bf(w[1]) << 16);
    p.y = (unsigned)f2bf(w[2]) | ((unsigned)f2bf(w[3]) << 16);
    wpk[i] = p;
}

// ---------------- phase 1: gather+aggregate, 3 planes/block ------------------
// grid = 8 groups x 125 chunks = 1000 blocks. group g handles planes
// {g, g+8, g+16} (all == g mod 8 -> same XCD under blockIdx%8 heuristic), so
// each XCD's L2 holds 3 planes (1.9 MB) for the entire kernel.
// Records staged in LDS: idx byte-offsets + weights pre-unpacked to f32.
// agg layout: (n, b, t, c, h) bf16 -> one uint2 store per (thread, plane).
__global__ __launch_bounds__(256) void aggregate_kernel(
    const float* __restrict__ x,
    const int*   __restrict__ idxf,
    const uint2* __restrict__ wpk,
    float* __restrict__ out,
    unsigned short* __restrict__ agg)
{
    const int g     = blockIdx.x & 7;
    const int chunk = blockIdx.x >> 3;       // 0..124
    const int n0    = chunk * NPC;
    const int tid   = threadIdx.x;

    __shared__ int   lds_idx[NPC * KK];      // 5.4 KB
    __shared__ float lds_w[NPC * KK][HH];    // 21.8 KB

    // ---- stage records (coalesced), unpack weights to f32 once ----
    const int rbase = n0 * KK;               // record index of chunk start
    for (int j = tid; j < NPC * KK; j += 256) {
        lds_idx[j] = idxf[rbase + j];
        const uint2 wp = wpk[rbase + j];
        lds_w[j][0] = bf2f(wp.x & 0xffffu);
        lds_w[j][1] = bf2f(wp.x >> 16);
        lds_w[j][2] = bf2f(wp.y & 0xffffu);
        lds_w[j][3] = bf2f(wp.y >> 16);
    }
    __syncthreads();

    // plane set for this group
    int plane[PPG], bb[PPG], tt[PPG];
    const char* xb[PPG];
    #pragma unroll
    for (int p = 0; p < PPG; ++p) {
        plane[p] = g + 8 * p;                // 0..23
        bb[p] = plane[p] / T_IN;
        tt[p] = plane[p] % T_IN;
        xb[p] = (const char*)(x + (long)plane[p] * NN * CC);
    }

    const int c  = tid & 15;
    const int nl = tid >> 4;                 // 0..15
    const int cb = c * 4;                    // byte offset of channel

    for (int it = 0; it < NPC / 16; ++it) {
        const int n_local = nl + 16 * it;    // 0..79
        const int n  = n0 + n_local;
        const int rb = n_local * KK;

        float a0[PPG], a1[PPG], a2[PPG], a3[PPG];
        #pragma unroll
        for (int p = 0; p < PPG; ++p) { a0[p]=0.f; a1[p]=0.f; a2[p]=0.f; a3[p]=0.f; }

        #pragma unroll
        for (int k = 0; k < KK; ++k) {
            const int   off = lds_idx[rb + k] + cb;
            const float w0 = lds_w[rb + k][0];
            const float w1 = lds_w[rb + k][1];
            const float w2 = lds_w[rb + k][2];
            const float w3 = lds_w[rb + k][3];
            float gv[PPG];
            #pragma unroll
            for (int p = 0; p < PPG; ++p)
                gv[p] = *(const float*)(xb[p] + off);
            #pragma unroll
            for (int p = 0; p < PPG; ++p) {
                a0[p] += gv[p] * w0;
                a1[p] += gv[p] * w1;
                a2[p] += gv[p] * w2;
                a3[p] += gv[p] * w3;
            }
        }

        #pragma unroll
        for (int p = 0; p < PPG; ++p) {
            uint2 pk;
            pk.x = (unsigned)f2bf(a0[p]) | ((unsigned)f2bf(a1[p]) << 16);
            pk.y = (unsigned)f2bf(a2[p]) | ((unsigned)f2bf(a3[p]) << 16);
            // agg (n,b,t,c,h): uint2 index = ((n*NB+b)*T_IN+t)*CC + c
            ((uint2*)agg)[(((n * NB + bb[p]) * T_IN + tt[p]) * CC) + c] = pk;
        }
    }

    // ---- passthrough for the 3 planes: out[b,t,chunk] = x[b,t,chunk] ----
    #pragma unroll
    for (int p = 0; p < PPG; ++p) {
        const float4* src = (const float4*)(x + (long)plane[p] * NN * CC + n0 * CC);
        float4* dst = (float4*)(out + (long)(bb[p] * T_OUT_ + tt[p]) * NN * CC + n0 * CC);
        for (int i = tid; i < NPC * CC / 4; i += 256)   // 320 float4
            dst[i] = src[i];
    }
}

// ---------------- phase 2: 48-term shrink matmul + SELU ----------------
__global__ __launch_bounds__(384) void shrink_kernel(
    const unsigned short* __restrict__ agg,
    const float* __restrict__ Wm, const float* __restrict__ bias,
    float* __restrict__ out)
{
    const int n   = blockIdx.x;
    const int tid = threadIdx.x;

    __shared__ float a_s[NB * T_IN * CC * HH];  // 1536 floats, [b][t][c][h]
    __shared__ float W_s[O_OUT * JJ];
    __shared__ float b_s[O_OUT];

    // this node's agg: 1536 bf16 = 3072 B contiguous, 384 x uint2
    const uint2 v = ((const uint2*)(agg + (long)n * (NB * T_IN * CC * HH)))[tid];
    a_s[4 * tid + 0] = bf2f(v.x & 0xffffu);
    a_s[4 * tid + 1] = bf2f(v.x >> 16);
    a_s[4 * tid + 2] = bf2f(v.y & 0xffffu);
    a_s[4 * tid + 3] = bf2f(v.y >> 16);
    for (int i = tid; i < O_OUT * JJ; i += 384) W_s[i] = Wm[i];
    if (tid < O_OUT) b_s[tid] = bias[tid];
    __syncthreads();

    const int c2   = tid & 15;
    const int rest = tid >> 4;      // 0..23
    const int o    = rest % O_OUT;
    const int b2   = rest / O_OUT;

    float y = b_s[o];
    #pragma unroll
    for (int t = 0; t < T_IN; ++t) {
        const int ab = ((b2 * T_IN + t) * CC + c2) * HH;
        const int wb = o * JJ + t * HH;
        #pragma unroll
        for (int h = 0; h < HH; ++h)
            y += a_s[ab + h] * W_s[wb + h];
    }

    const float kScale = 1.0507009873554805f;
    const float kAlpha = 1.6732632423543772f;
    y = (y > 0.0f) ? kScale * y : kScale * kAlpha * expm1f(y);

    out[((long)(b2 * T_OUT_ + T_IN + o) * NN + n) * CC + c2] = y;
}

extern "C" void kernel_launch(void* const* d_in, const int* in_sizes, int n_in,
                              void* d_out, int out_size, void* d_ws, size_t ws_size,
                              hipStream_t stream) {
    const float* x     = (const float*)d_in[0];
    const int*   nodes = (const int*)  d_in[1];
    const float* dists = (const float*)d_in[2];
    const float* Wm    = (const float*)d_in[3];
    const float* bias  = (const float*)d_in[4];
    float* out = (float*)d_out;

    // ws layout: [0,4)=sigma | 256: idxf (N*K int) | wpk (N*K uint2) |
    // agg (N*B*T*C*H bf16, 30.72 MB)  => ~32.8 MB total
    char* ws = (char*)d_ws;
    unsigned int*   sigma_bits = (unsigned int*)ws;
    int*            idxf = (int*)(ws + 256);
    uint2*          wpk  = (uint2*)(ws + 256 + 680000);
    unsigned short* agg  = (unsigned short*)(ws + 256 + 680000 + 1360000);

    hipMemsetAsync(d_ws, 0, 4, stream);  // sigma slot (ws is poisoned 0xAA)

    const int nd = in_sizes[2];  // N*K
    sigma_reduce_kernel<<<256, 256, 0, stream>>>(dists, nd, sigma_bits);
    weights_kernel<<<(NN * KK + 255) / 256, 256, 0, stream>>>(
        nodes, dists, sigma_bits, idxf, wpk);
    aggregate_kernel<<<8 * NCHUNK, 256, 0, stream>>>(x, idxf, wpk, out, agg);
    shrink_kernel<<<NN, 384, 0, stream>>>(agg, Wm, bias, out);
}